// Round 8
// baseline (194.120 us; speedup 1.0000x reference)
//
#include <hip/hip_runtime.h>

#define EPS 1e-5f

typedef __bf16 bf16x8 __attribute__((ext_vector_type(8)));
typedef float  f32x4  __attribute__((ext_vector_type(4)));

__device__ __forceinline__ unsigned short f2bf(float f) {
  unsigned int u = __float_as_uint(f);
  unsigned int r = (u + 0x7fffu + ((u >> 16) & 1u)) >> 16;
  return (unsigned short)r;
}
// native RNE bf16 pair-pack: compiler emits v_cvt_pk_bf16_f32 (bit-identical to
// f2bf for normal values; ~1-3 ops vs ~10 for the manual bit-twiddle pair)
__device__ __forceinline__ unsigned int pack_bf16(float lo, float hi) {
  unsigned short a = __builtin_bit_cast(unsigned short, (__bf16)lo);
  unsigned short b = __builtin_bit_cast(unsigned short, (__bf16)hi);
  return (unsigned int)a | ((unsigned int)b << 16);
}
// silu via v_rcp_f32 (avoids precise-div sequence; ~2^-22 rel err, fine at bf16 tol)
__device__ __forceinline__ float silu(float y) {
  return y * __builtin_amdgcn_rcpf(1.f + __expf(-y));
}

// ---------------- prep: ALL weight/activation reads coalesced via per-block LDS
// tiles, kept WIDE (380 parallel blocks — do NOT re-serialize into few blocks:
// a 5-block LDS-tiled prep measured ~16us WORSE by sitting alone on the critical
// path). Per-lane strided gathers (64 cachelines per wave-load) measured
// ~18-20us for the transpose paths alone (R1 vs R2 non-rel A/B).
// blk 0..99    : feat/featT = SiLU(BN(conv1x1(x,w1))), 8 px/block; w1 staged in
//                LDS [128][129] (pad -> 2-way banks = free), exact s0..s3 numerics
// blk 100..171 : pack wr2 -> MFMA A-frag bf16 (frag f = tap*32+ks*8+m8), LDS-tiled
// blk 172..203 : wave-parallel prefix sums of wr1 rows -> Pfx[o][0..256]
// blk 204..347 : transpose wr2 -> Wt[tap][i][o] fp32, LDS-tiled
// blk 348..379 : transpose wr1 -> wr1T[i][o] fp32, LDS-tiled
// NOTE: Wt/wr1T transposed workspace copies are LOAD-BEARING for rel's const
// path (coalesced reads; raw wr1/wr2 reads in rel thrash L2 and evict Apack —
// measured FETCH 7MB->180MB, rel 91->259us). Do not "simplify" away.
__global__ void prep_kernel(const float* __restrict__ x, const float* __restrict__ w1,
                            const float* __restrict__ g1, const float* __restrict__ b1,
                            const float* __restrict__ m1, const float* __restrict__ v1,
                            const float* __restrict__ wr2, const float* __restrict__ wr1,
                            float* __restrict__ feat, float* __restrict__ featT,
                            unsigned short* __restrict__ Apack, float* __restrict__ Pfx,
                            float* __restrict__ Wt, float* __restrict__ wr1T) {
  __shared__ __align__(16) float sbuf[18496];   // 73984 B, unioned across paths
  int blk = blockIdx.x;
  int tid = threadIdx.x;
  if (blk < 100) {
    // ---- feat: 8 px per block, w1 LDS-staged ----
    float* w1s = sbuf;               // [128][129]
    float* xvb = sbuf + 16512;       // [8][128]
    int p0 = blk * 8;
    int b = p0 / 400, pb = p0 % 400;   // 8 | 400 -> no b straddle
    const float4* w14 = (const float4*)w1;
    for (int u = tid; u < 4096; u += 256) {        // coalesced f4 reads of w1
      float4 v = w14[u];
      int c = u >> 5, i4 = (u & 31) * 4;
      float* d = w1s + c * 129 + i4;
      d[0] = v.x; d[1] = v.y; d[2] = v.z; d[3] = v.w;
    }
    for (int u = tid; u < 1024; u += 256) {        // x columns (unavoidable gather)
      int pl = u >> 7, c = u & 127;
      xvb[pl * 128 + c] = x[(b * 128 + c) * 400 + pb + pl];
    }
    __syncthreads();
    int c = tid & 127, pg = tid >> 7;
    float a0[4], a1[4], a2[4], a3[4];
#pragma unroll
    for (int q = 0; q < 4; ++q) { a0[q] = a1[q] = a2[q] = a3[q] = 0.f; }
    const float* wr = w1s + c * 129;
#pragma unroll 8
    for (int k = 0; k < 32; ++k) {
      float w0 = wr[4 * k], w1v = wr[4 * k + 1], w2v = wr[4 * k + 2], w3v = wr[4 * k + 3];
#pragma unroll
      for (int q = 0; q < 4; ++q) {
        float4 xx = *(const float4*)&xvb[(pg * 4 + q) * 128 + 4 * k];
        a0[q] += w0 * xx.x; a1[q] += w1v * xx.y; a2[q] += w2v * xx.z; a3[q] += w3v * xx.w;
      }
    }
    float sc = g1[c] * rsqrtf(v1[c] + EPS);
    float sh = b1[c] - m1[c] * sc;
#pragma unroll
    for (int q = 0; q < 4; ++q) {
      float s = (a0[q] + a1[q]) + (a2[q] + a3[q]);   // exact original grouping
      float f = silu(s * sc + sh);
      int p = pb + pg * 4 + q;
      feat[(b * 400 + p) * 128 + c] = f;     // coalesced
      featT[(b * 128 + c) * 400 + p] = f;    // scatter (layout needed by rel)
    }
  } else if (blk < 172) {
    // ---- Apack: LDS-tile the wr2 slice, emit bf16 frags ----
    int w_ = blk - 100;                       // 0..71
    int tap = w_ >> 3, ks = (w_ >> 1) & 3, o0 = (w_ & 1) * 64;
    const float4* s4 = (const float4*)wr2;
    for (int u = tid; u < 4608; u += 256) {   // 64 o x 72 f4, coalesced per row-chunk
      int o = u / 72, r = u - o * 72;
      float4 v = s4[(size_t)(o0 + o) * 288 + 72 * ks + r];
      float* d = sbuf + o * 289 + r * 4;
      d[0] = v.x; d[1] = v.y; d[2] = v.z; d[3] = v.w;
    }
    __syncthreads();
    int wv = tid >> 6, lane = tid & 63;
    int f = w_ * 4 + wv;
    int o_l = wv * 16 + (lane & 15);
    int ib = (lane >> 4) * 8;
    unsigned short* dst = Apack + ((size_t)f * 64 + lane) * 8;
#pragma unroll
    for (int j = 0; j < 8; ++j)
      dst[j] = f2bf(sbuf[o_l * 289 + (ib + j) * 9 + tap]);
  } else if (blk < 204) {
    // ---- Pfx: prefix sums of wr1 rows (reads already coalesced f4) ----
    int o = (blk - 172) * 4 + (tid >> 6);
    int lane = tid & 63;
    float4 wv = ((const float4*)(wr1 + o * 256))[lane];
    float p0 = wv.x, p1 = p0 + wv.y, p2 = p1 + wv.z, p3 = p2 + wv.w;
    float v = p3;
#pragma unroll
    for (int d = 1; d < 64; d <<= 1) {
      float t = __shfl_up(v, d);
      if (lane >= d) v += t;
    }
    float off = v - p3;
    float* Po = Pfx + o * 257;
    if (lane == 0) Po[0] = 0.f;
    Po[lane * 4 + 1] = off + p0;
    Po[lane * 4 + 2] = off + p1;
    Po[lane * 4 + 3] = off + p2;
    Po[lane * 4 + 4] = off + p3;
  } else if (blk < 348) {
    // ---- Wt transpose: LDS-tile (8 i x 9 tap per o), coalesced both sides ----
    int blk_ = blk - 204;                     // 0..143
    int base = blk_ * 1024;
    int tap = blk_ >> 4;                      // 16 blocks per tap, no straddle
    int i0 = (blk_ & 15) * 8;
    const float4* s4 = (const float4*)wr2;
    int i0q = (9 * i0) >> 2;                  // i0 multiple of 8 -> exact
    for (int u = tid; u < 2304; u += 256) {   // 128 o x 18 f4
      int o = u / 18, r = u - o * 18;
      float4 v = s4[o * 288 + i0q + r];
      float* d = sbuf + o * 73 + r * 4;
      d[0] = v.x; d[1] = v.y; d[2] = v.z; d[3] = v.w;
    }
    __syncthreads();
#pragma unroll
    for (int k = 0; k < 4; ++k) {
      int idx = base + k * 256 + tid;
      int o = idx & 127, il = ((idx & 16383) >> 7) - i0;
      Wt[idx] = sbuf[o * 73 + il * 9 + tap];  // lanes: o-consecutive, 2-way banks
    }
  } else {
    // ---- wr1T transpose: LDS-tile (8 i per o) ----
    int blk_ = blk - 348;                     // 0..31
    int base = blk_ * 1024;
    int i0 = base >> 7;
    const float4* s4 = (const float4*)wr1;
    {
      int o = tid >> 1, r = tid & 1;          // 128 o x 2 f4
      float4 v = s4[o * 64 + (i0 >> 2) + r];
      float* d = sbuf + o * 9 + r * 4;
      d[0] = v.x; d[1] = v.y; d[2] = v.z; d[3] = v.w;
    }
    __syncthreads();
#pragma unroll
    for (int k = 0; k < 4; ++k) {
      int idx = base + k * 256 + tid;
      int o = idx & 127, il = (idx >> 7) - i0;
      wr1T[idx] = sbuf[o * 9 + il];
    }
  }
}

// ---------------- merged relational kernel (one block owns one q-row end-to-end;
// out fused; NO cross-block communication — no fences (a per-block
// __threadfence() election measured rel 91->196us, WRITE 0.6->3.4MB).
// blk 0..399   : main path, q in [200,400): TWO half-image passes, FULLY UNROLLED
//                (runtime `for half` loop made the compiler spill the MFMA
//                accumulator to scratch: WRITE_SIZE 0.6->29.6MB, rel 91->105us.
//                #pragma unroll restores straight-line per-pass codegen with
//                acc in AGPRs — keep it).
// blk 400..799 : const path, q in [0,200) (r1 spatially constant -> 9-pattern
//                shortcut), out row computed in-block.
// L2 note: const blocks partially co-run with main; safe because their weight
// reads are the coalesced Wt/wr1T copies — hot set fits each XCD's 4MB L2.
// VALU note (R8): phase1 restructured so each thread owns a fixed channel-octet
// (plane = tid>>5) — 32 LDS constant reads hoisted out of the p-loop — and the
// bf16 pack uses native casts (v_cvt_pk_bf16_f32, RNE == f2bf). Epilogue loops
// reordered (mt outer) so sc2/sh2/w3c are read 48x not 192x. Numerics identical.
__global__ __launch_bounds__(512, 4) void rel_kernel(
    const float* __restrict__ feat, const float* __restrict__ featT,
    const float* __restrict__ wr1T, const float* __restrict__ Pfx,
    const float* __restrict__ gr1, const float* __restrict__ br1,
    const float* __restrict__ mr1, const float* __restrict__ vr1,
    const unsigned short* __restrict__ Apack, const float* __restrict__ Wt,
    const float* __restrict__ gr2, const float* __restrict__ br2,
    const float* __restrict__ mr2, const float* __restrict__ vr2,
    const float* __restrict__ wr3,
    const float* __restrict__ gr3, const float* __restrict__ br3,
    const float* __restrict__ mr3, const float* __restrict__ vr3,
    const float* __restrict__ x, const float* __restrict__ w2,
    const float* __restrict__ g2, const float* __restrict__ b2,
    const float* __restrict__ m2, const float* __restrict__ v2,
    float* __restrict__ out) {

  __shared__ __align__(16) unsigned short r1f[16 * 221 * 8];   // 56576 B
  __shared__ float f0s[220], f1s[220], scoreS[208];
  __shared__ float wB0s[128], wB1s[128];
  __shared__ float sc1[128], sh1[128], sc2[128], sh2[128], w3c[128];
  __shared__ __align__(16) float attT[128];
  __shared__ __align__(16) float fA[256];
  __shared__ float r1c[128], AvS[128];
  __shared__ float vS[9 * 128];
  __shared__ float spS[9];
  __shared__ float spP[400];

  int tid = threadIdx.x, lane = tid & 63, wid = tid >> 6;
  int blk = blockIdx.x;

  if (tid < 128) {
    float s1 = gr1[tid] * rsqrtf(vr1[tid] + EPS); sc1[tid] = s1; sh1[tid] = br1[tid] - mr1[tid] * s1;
    float s2 = gr2[tid] * rsqrtf(vr2[tid] + EPS); sc2[tid] = s2; sh2[tid] = br2[tid] - mr2[tid] * s2;
    w3c[tid] = wr3[tid];
    attT[tid] = 0.f; AvS[tid] = 0.f;
  }
  float s3 = gr3[0] * rsqrtf(vr3[0] + EPS);
  float sh3 = br3[0] - mr3[0] * s3;

  if (blk < 400) {
    // ================= main path: one block = one q row, two half passes =========
    int b = blk / 200, q = 200 + blk % 200;
    int c0 = (q * 256) / 400, c1 = c0 + 1;
    if (tid < 128) {
      const float* Po = Pfx + tid * 257;
      int e0 = min(256, 400 * c0 + 400 - 256 * q);   // s0 is always 0
      wB0s[tid] = Po[e0];
      float wv = 0.f;
      if (c1 < 256) {
        int s1i = min(256, max(0, 400 * c1 - 256 * q));
        wv = Po[256] - Po[s1i];
      }
      wB1s[tid] = wv;
    }

    int wm = wid & 1, wn = wid >> 1;
    int ntcnt = (wn == 0) ? 4 : 3;
    int n16 = lane & 15, quad = lane >> 4;
    const char* wbase = (const char*)Apack + (size_t)((wm * 4) * 64 + lane) * 16;

#pragma unroll
    for (int half = 0; half < 2; ++half) {
      if (tid < 220) {
        int p = tid + 180 * half;
        f0s[tid] = featT[(b * 128 + (c0 - 128)) * 400 + p];                  // coalesced
        f1s[tid] = (c1 < 256) ? featT[(b * 128 + (c1 - 128)) * 400 + p] : 0.f;
      }
      if (tid < 208) scoreS[tid] = 0.f;
      __syncthreads();

      // phase1: r1 = SiLU(BN(wB0*f0 + wB1*f1)) -> LDS bf16 fragment-major.
      // Fixed plane per thread: per-channel constants hoisted out of the p-loop.
      {
        int plane = tid >> 5, pl = tid & 31;
        int cb = (plane >> 2) * 32 + (plane & 3) * 8;
        float wAr[8], wBr[8], scr[8], shr[8];
#pragma unroll
        for (int j = 0; j < 8; ++j) {
          int c = cb + j;
          wAr[j] = wB0s[c]; wBr[j] = wB1s[c]; scr[j] = sc1[c]; shr[j] = sh1[c];
        }
        unsigned short* rowbase = &r1f[plane * 221 * 8];
#pragma unroll
        for (int k = 0; k < 7; ++k) {
          int p = pl + 32 * k;
          if (p < 220) {
            float fa0 = f0s[p], fa1 = f1s[p];
            unsigned int pk[4];
#pragma unroll
            for (int jp = 0; jp < 4; ++jp) {
              float y0 = wAr[2 * jp] * fa0 + wBr[2 * jp] * fa1;
              y0 = y0 * scr[2 * jp] + shr[2 * jp];
              float y1 = wAr[2 * jp + 1] * fa0 + wBr[2 * jp + 1] * fa1;
              y1 = y1 * scr[2 * jp + 1] + shr[2 * jp + 1];
              pk[jp] = pack_bf16(silu(y0), silu(y1));
            }
            *(uint4*)&rowbase[p * 8] = make_uint4(pk[0], pk[1], pk[2], pk[3]);
          }
        }
      }
      if (tid < 16) *(uint4*)&r1f[(tid * 221 + 220) * 8] = make_uint4(0, 0, 0, 0);

      int hA[4], wA[4], poA[4]; bool pov[4];
#pragma unroll
      for (int t = 0; t < 4; ++t) {
        int po = (wn + 4 * t) * 16 + n16;
        poA[t] = po; pov[t] = po < 200;
        int pg = half * 200 + po;
        hA[t] = pg / 20; wA[t] = pg - 20 * hA[t];
      }
      f32x4 acc[4][4];
#pragma unroll
      for (int mt = 0; mt < 4; ++mt)
#pragma unroll
        for (int t = 0; t < 4; ++t) acc[mt][t] = f32x4{0.f, 0.f, 0.f, 0.f};

      __syncthreads();   // r1f visible — NO barriers through the K-loop

      for (int tap = 0; tap < 9; ++tap) {
        int dy = tap / 3 - 1, dx = tap % 3 - 1;
        int pp[4];
#pragma unroll
        for (int t = 0; t < 4; ++t) {
          int hh = hA[t] + dy, ww = wA[t] + dx;
          bool valid = pov[t] & (hh >= 0) & (hh < 20) & (ww >= 0) & (ww < 20);
          pp[t] = valid ? (hh - 9 * half) * 20 + ww : 220;
        }
#pragma unroll
        for (int ks = 0; ks < 4; ++ks) {
          const char* wp = wbase + (size_t)(tap * 4 + ks) * 8192;
          bf16x8 af0 = *(const bf16x8*)(wp);
          bf16x8 af1 = *(const bf16x8*)(wp + 1024);
          bf16x8 af2 = *(const bf16x8*)(wp + 2048);
          bf16x8 af3 = *(const bf16x8*)(wp + 3072);
          int pbase = (ks * 4 + quad) * 221;
#pragma unroll
          for (int t = 0; t < 4; ++t) {
            if (t < ntcnt) {                 // wave-uniform
              bf16x8 bfr = *(const bf16x8*)&r1f[(pbase + pp[t]) * 8];
              acc[0][t] = __builtin_amdgcn_mfma_f32_16x16x32_bf16(af0, bfr, acc[0][t], 0, 0, 0);
              acc[1][t] = __builtin_amdgcn_mfma_f32_16x16x32_bf16(af1, bfr, acc[1][t], 0, 0, 0);
              acc[2][t] = __builtin_amdgcn_mfma_f32_16x16x32_bf16(af2, bfr, acc[2][t], 0, 0, 0);
              acc[3][t] = __builtin_amdgcn_mfma_f32_16x16x32_bf16(af3, bfr, acc[3][t], 0, 0, 0);
            }
          }
        }
      }

      // epilogue: BN2+SiLU, conv3 dot, reduce to scoreS (mt outer: 48 LDS reads,
      // per-t accumulation order identical to original)
      {
        float ps[4] = {0.f, 0.f, 0.f, 0.f};
#pragma unroll
        for (int mt = 0; mt < 4; ++mt) {
          float s2r[4], sh2r[4], w3r[4];
#pragma unroll
          for (int r = 0; r < 4; ++r) {
            int o = wm * 64 + mt * 16 + quad * 4 + r;
            s2r[r] = sc2[o]; sh2r[r] = sh2[o]; w3r[r] = w3c[o];
          }
#pragma unroll
          for (int t = 0; t < 4; ++t) {
            if (t < ntcnt) {
#pragma unroll
              for (int r = 0; r < 4; ++r) {
                float y = acc[mt][t][r] * s2r[r] + sh2r[r];
                ps[t] += silu(y) * w3r[r];
              }
            }
          }
        }
#pragma unroll
        for (int t = 0; t < 4; ++t) {
          if (t < ntcnt) {
            float p = ps[t];
            p += __shfl_xor(p, 16);
            p += __shfl_xor(p, 32);
            if (quad == 0 && pov[t]) atomicAdd(&scoreS[poA[t]], p);
          }
        }
      }
      __syncthreads();

      if (tid < 200) scoreS[tid] = silu(scoreS[tid] * s3 + sh3);
      __syncthreads();

      {
        int c = tid & 127, part = tid >> 7;
        float s = 0.f;
        int j0 = part * 50;
        const float* fb = feat + ((size_t)(b * 400 + half * 200 + j0)) * 128 + c;
#pragma unroll 10
        for (int j = 0; j < 50; ++j)
          s += scoreS[j0 + j] * fb[(size_t)j * 128];
        atomicAdd(&attT[c], s);
      }
      __syncthreads();   // attT pass done; also guards scoreS/f0s/r1f reuse next pass
    }

    // fused out: att row complete in LDS
    {
      int c = tid >> 2, sub = tid & 3;
      const float4* w4 = (const float4*)(w2 + c * 128 + sub * 32);
      const float4* v4 = (const float4*)(attT + sub * 32);
      float s0 = 0.f, s1 = 0.f, s2v = 0.f, s3v = 0.f;
#pragma unroll
      for (int i = 0; i < 8; ++i) {
        float4 wv = w4[i], xx = v4[i];
        s0 += wv.x * xx.x; s1 += wv.y * xx.y; s2v += wv.z * xx.z; s3v += wv.w * xx.w;
      }
      float s = (s0 + s1) + (s2v + s3v);
      s += __shfl_xor(s, 1);
      s += __shfl_xor(s, 2);
      if (sub == 0) {
        float scc = g2[c] * rsqrtf(v2[c] + EPS);
        float y = s * scc + (b2[c] - m2[c] * scc);
        int xi = (b * 128 + c) * 400 + q;
        out[xi] = silu(y) + x[xi];
      }
    }
  } else {
    // ================= const path (q < 200): r1 constant over pixels =================
    int cidx = blk - 400;
    int b = cidx / 200, q = cidx % 200;
    if (tid < 256) {
      int u = q * 256 + tid; int c = u / 400, i2 = u - c * 400;
      fA[tid] = featT[(b * 128 + c) * 400 + i2];           // coalesced
    }
    for (int k = tid; k < 1152; k += 512) vS[k] = 0.f;
    __syncthreads();
    {
      int o = tid & 127, part = tid >> 7;
      const float* wt = wr1T + part * 64 * 128 + o;        // coalesced across o
      const float* fv = fA + part * 64;
      float a = 0.f;
#pragma unroll 8
      for (int k = 0; k < 64; ++k) a += wt[k * 128] * fv[k];
      atomicAdd(&AvS[o], a);
    }
    __syncthreads();
    if (tid < 128) r1c[tid] = silu(AvS[tid] * sc1[tid] + sh1[tid]);
    __syncthreads();
    {
      int o = tid & 127, part = tid >> 7;
      const float* rc = r1c + part * 32;
      for (int tap = 0; tap < 9; ++tap) {
        const float* wt = Wt + tap * 16384 + part * 32 * 128 + o;
        float s = 0.f;
#pragma unroll 8
        for (int i2 = 0; i2 < 32; ++i2) s += wt[i2 * 128] * rc[i2];
        atomicAdd(&vS[tap * 128 + o], s);
      }
    }
    __syncthreads();
    for (int pat = wid; pat < 9; pat += 8) {
      int ry = pat / 3, rx = pat % 3;
      float ps = 0.f;
      for (int oo = lane; oo < 128; oo += 64) {
        float y = 0.f;
#pragma unroll
        for (int dy = -1; dy <= 1; ++dy) {
          if ((ry == 0 && dy < 0) || (ry == 2 && dy > 0)) continue;
#pragma unroll
          for (int dx = -1; dx <= 1; ++dx) {
            if ((rx == 0 && dx < 0) || (rx == 2 && dx > 0)) continue;
            y += vS[((dy + 1) * 3 + (dx + 1)) * 128 + oo];
          }
        }
        y = y * sc2[oo] + sh2[oo];
        ps += silu(y) * w3c[oo];
      }
#pragma unroll
      for (int sft = 32; sft >= 1; sft >>= 1) ps += __shfl_xor(ps, sft);
      if (lane == 0) spS[pat] = silu(ps * s3 + sh3);
    }
    __syncthreads();

    for (int p = tid; p < 400; p += 512) {
      int r = p / 20, cm = p - 20 * r;
      int ry = (r == 0) ? 0 : (r == 19) ? 2 : 1;
      int rx = (cm == 0) ? 0 : (cm == 19) ? 2 : 1;
      spP[p] = spS[ry * 3 + rx];
    }
    __syncthreads();
    {
      int c = tid & 127, part = tid >> 7;
      const float* fb = feat + ((size_t)(b * 400) + part * 100) * 128 + c;
      const float* sp = spP + part * 100;
      float s = 0.f;
#pragma unroll 10
      for (int j = 0; j < 100; ++j) s += sp[j] * fb[(size_t)j * 128];
      atomicAdd(&attT[c], s);
    }
    __syncthreads();
    // fused out: att row complete in LDS (attT); global att never touched
    {
      int c = tid >> 2, sub = tid & 3;
      const float4* w4 = (const float4*)(w2 + c * 128 + sub * 32);
      const float4* v4 = (const float4*)(attT + sub * 32);
      float s0 = 0.f, s1 = 0.f, s2v = 0.f, s3v = 0.f;
#pragma unroll
      for (int i = 0; i < 8; ++i) {
        float4 wv = w4[i], xx = v4[i];
        s0 += wv.x * xx.x; s1 += wv.y * xx.y; s2v += wv.z * xx.z; s3v += wv.w * xx.w;
      }
      float s = (s0 + s1) + (s2v + s3v);
      s += __shfl_xor(s, 1);
      s += __shfl_xor(s, 2);
      if (sub == 0) {
        float scc = g2[c] * rsqrtf(v2[c] + EPS);
        float y = s * scc + (b2[c] - m2[c] * scc);
        int xi = (b * 128 + c) * 400 + q;
        out[xi] = silu(y) + x[xi];
      }
    }
  }
}

extern "C" void kernel_launch(void* const* d_in, const int* in_sizes, int n_in,
                              void* d_out, int out_size, void* d_ws, size_t ws_size,
                              hipStream_t stream) {
  const float* x   = (const float*)d_in[0];
  const float* w1  = (const float*)d_in[1];
  const float* g1  = (const float*)d_in[2];
  const float* b1  = (const float*)d_in[3];
  const float* m1  = (const float*)d_in[4];
  const float* v1  = (const float*)d_in[5];
  const float* w2  = (const float*)d_in[6];
  const float* g2  = (const float*)d_in[7];
  const float* b2  = (const float*)d_in[8];
  const float* m2  = (const float*)d_in[9];
  const float* v2  = (const float*)d_in[10];
  const float* wr1 = (const float*)d_in[11];
  const float* gr1 = (const float*)d_in[12];
  const float* br1 = (const float*)d_in[13];
  const float* mr1 = (const float*)d_in[14];
  const float* vr1 = (const float*)d_in[15];
  const float* wr2 = (const float*)d_in[16];
  const float* gr2 = (const float*)d_in[17];
  const float* br2 = (const float*)d_in[18];
  const float* mr2 = (const float*)d_in[19];
  const float* vr2 = (const float*)d_in[20];
  const float* wr3 = (const float*)d_in[21];
  const float* gr3 = (const float*)d_in[22];
  const float* br3 = (const float*)d_in[23];
  const float* mr3 = (const float*)d_in[24];
  const float* vr3 = (const float*)d_in[25];
  float* out = (float*)d_out;

  char* ws = (char*)d_ws;
  float*          feat  = (float*)ws;                        // 409600 B
  unsigned short* Apack = (unsigned short*)(ws + 819200);    // 294912 B
  float*          Pfx   = (float*)(ws + 1114112);            // 131584 B
  float*          Wt    = (float*)(ws + 1245696);            // 589824 B
  float*          featT = (float*)(ws + 1901056);            // 409600 B
  float*          wr1T  = (float*)(ws + 2310656);            // 131072 B

  prep_kernel<<<380, 256, 0, stream>>>(x, w1, g1, b1, m1, v1, wr2, wr1,
                                       feat, featT, Apack, Pfx, Wt, wr1T);
  rel_kernel<<<800, 512, 0, stream>>>(feat, featT, wr1T, Pfx, gr1, br1, mr1, vr1,
                                      Apack, Wt,
                                      gr2, br2, mr2, vr2, wr3, gr3, br3, mr3, vr3,
                                      x, w2, g2, b2, m2, v2, out);
}

// Round 9
// 192.541 us; speedup vs baseline: 1.0082x; 1.0082x over previous
//
#include <hip/hip_runtime.h>

#define EPS 1e-5f

typedef __bf16 bf16x8 __attribute__((ext_vector_type(8)));
typedef float  f32x4  __attribute__((ext_vector_type(4)));

// native RNE bf16 pair-pack: compiler emits v_cvt_pk_bf16_f32 (bit-identical to
// manual round-to-nearest-even bit-twiddle for normal values, ~1-2 ops vs ~10).
// ZERO extra register cost — safe under this kernel's tight 128-reg budget.
__device__ __forceinline__ unsigned int pack_bf16(float lo, float hi) {
  unsigned short a = __builtin_bit_cast(unsigned short, (__bf16)lo);
  unsigned short b = __builtin_bit_cast(unsigned short, (__bf16)hi);
  return (unsigned int)a | ((unsigned int)b << 16);
}
__device__ __forceinline__ unsigned short f2bf(float f) {
  return __builtin_bit_cast(unsigned short, (__bf16)f);
}
// silu via v_rcp_f32 (avoids precise-div sequence; ~2^-22 rel err, fine at bf16 tol)
__device__ __forceinline__ float silu(float y) {
  return y * __builtin_amdgcn_rcpf(1.f + __expf(-y));
}

// ---------------- prep: ALL weight/activation reads coalesced via per-block LDS
// tiles, kept WIDE (380 parallel blocks — do NOT re-serialize into few blocks:
// a 5-block LDS-tiled prep measured ~16us WORSE by sitting alone on the critical
// path). Per-lane strided gathers (64 cachelines per wave-load) measured
// ~18-20us for the transpose paths alone (R1 vs R2 non-rel A/B).
// blk 0..99    : feat/featT = SiLU(BN(conv1x1(x,w1))), 8 px/block; w1 staged in
//                LDS [128][129] (pad -> 2-way banks = free), exact s0..s3 numerics
// blk 100..171 : pack wr2 -> MFMA A-frag bf16 (frag f = tap*32+ks*8+m8), LDS-tiled
// blk 172..203 : wave-parallel prefix sums of wr1 rows -> Pfx[o][0..256]
// blk 204..347 : transpose wr2 -> Wt[tap][i][o] fp32, LDS-tiled
// blk 348..379 : transpose wr1 -> wr1T[i][o] fp32, LDS-tiled
// NOTE: Wt/wr1T transposed workspace copies are LOAD-BEARING for rel's const
// path (coalesced reads; raw wr1/wr2 reads in rel thrash L2 and evict Apack —
// measured FETCH 7MB->180MB, rel 91->259us). Do not "simplify" away.
__global__ void prep_kernel(const float* __restrict__ x, const float* __restrict__ w1,
                            const float* __restrict__ g1, const float* __restrict__ b1,
                            const float* __restrict__ m1, const float* __restrict__ v1,
                            const float* __restrict__ wr2, const float* __restrict__ wr1,
                            float* __restrict__ feat, float* __restrict__ featT,
                            unsigned short* __restrict__ Apack, float* __restrict__ Pfx,
                            float* __restrict__ Wt, float* __restrict__ wr1T) {
  __shared__ __align__(16) float sbuf[18496];   // 73984 B, unioned across paths
  int blk = blockIdx.x;
  int tid = threadIdx.x;
  if (blk < 100) {
    // ---- feat: 8 px per block, w1 LDS-staged ----
    float* w1s = sbuf;               // [128][129]
    float* xvb = sbuf + 16512;       // [8][128]
    int p0 = blk * 8;
    int b = p0 / 400, pb = p0 % 400;   // 8 | 400 -> no b straddle
    const float4* w14 = (const float4*)w1;
    for (int u = tid; u < 4096; u += 256) {        // coalesced f4 reads of w1
      float4 v = w14[u];
      int c = u >> 5, i4 = (u & 31) * 4;
      float* d = w1s + c * 129 + i4;
      d[0] = v.x; d[1] = v.y; d[2] = v.z; d[3] = v.w;
    }
    for (int u = tid; u < 1024; u += 256) {        // x columns (unavoidable gather)
      int pl = u >> 7, c = u & 127;
      xvb[pl * 128 + c] = x[(b * 128 + c) * 400 + pb + pl];
    }
    __syncthreads();
    int c = tid & 127, pg = tid >> 7;
    float a0[4], a1[4], a2[4], a3[4];
#pragma unroll
    for (int q = 0; q < 4; ++q) { a0[q] = a1[q] = a2[q] = a3[q] = 0.f; }
    const float* wr = w1s + c * 129;
#pragma unroll 8
    for (int k = 0; k < 32; ++k) {
      float w0 = wr[4 * k], w1v = wr[4 * k + 1], w2v = wr[4 * k + 2], w3v = wr[4 * k + 3];
#pragma unroll
      for (int q = 0; q < 4; ++q) {
        float4 xx = *(const float4*)&xvb[(pg * 4 + q) * 128 + 4 * k];
        a0[q] += w0 * xx.x; a1[q] += w1v * xx.y; a2[q] += w2v * xx.z; a3[q] += w3v * xx.w;
      }
    }
    float sc = g1[c] * rsqrtf(v1[c] + EPS);
    float sh = b1[c] - m1[c] * sc;
#pragma unroll
    for (int q = 0; q < 4; ++q) {
      float s = (a0[q] + a1[q]) + (a2[q] + a3[q]);   // exact original grouping
      float f = silu(s * sc + sh);
      int p = pb + pg * 4 + q;
      feat[(b * 400 + p) * 128 + c] = f;     // coalesced
      featT[(b * 128 + c) * 400 + p] = f;    // scatter (layout needed by rel)
    }
  } else if (blk < 172) {
    // ---- Apack: LDS-tile the wr2 slice, emit bf16 frags ----
    int w_ = blk - 100;                       // 0..71
    int tap = w_ >> 3, ks = (w_ >> 1) & 3, o0 = (w_ & 1) * 64;
    const float4* s4 = (const float4*)wr2;
    for (int u = tid; u < 4608; u += 256) {   // 64 o x 72 f4, coalesced per row-chunk
      int o = u / 72, r = u - o * 72;
      float4 v = s4[(size_t)(o0 + o) * 288 + 72 * ks + r];
      float* d = sbuf + o * 289 + r * 4;
      d[0] = v.x; d[1] = v.y; d[2] = v.z; d[3] = v.w;
    }
    __syncthreads();
    int wv = tid >> 6, lane = tid & 63;
    int f = w_ * 4 + wv;
    int o_l = wv * 16 + (lane & 15);
    int ib = (lane >> 4) * 8;
    unsigned short* dst = Apack + ((size_t)f * 64 + lane) * 8;
#pragma unroll
    for (int j = 0; j < 8; ++j)
      dst[j] = f2bf(sbuf[o_l * 289 + (ib + j) * 9 + tap]);
  } else if (blk < 204) {
    // ---- Pfx: prefix sums of wr1 rows (reads already coalesced f4) ----
    int o = (blk - 172) * 4 + (tid >> 6);
    int lane = tid & 63;
    float4 wv = ((const float4*)(wr1 + o * 256))[lane];
    float p0 = wv.x, p1 = p0 + wv.y, p2 = p1 + wv.z, p3 = p2 + wv.w;
    float v = p3;
#pragma unroll
    for (int d = 1; d < 64; d <<= 1) {
      float t = __shfl_up(v, d);
      if (lane >= d) v += t;
    }
    float off = v - p3;
    float* Po = Pfx + o * 257;
    if (lane == 0) Po[0] = 0.f;
    Po[lane * 4 + 1] = off + p0;
    Po[lane * 4 + 2] = off + p1;
    Po[lane * 4 + 3] = off + p2;
    Po[lane * 4 + 4] = off + p3;
  } else if (blk < 348) {
    // ---- Wt transpose: LDS-tile (8 i x 9 tap per o), coalesced both sides ----
    int blk_ = blk - 204;                     // 0..143
    int base = blk_ * 1024;
    int tap = blk_ >> 4;                      // 16 blocks per tap, no straddle
    int i0 = (blk_ & 15) * 8;
    const float4* s4 = (const float4*)wr2;
    int i0q = (9 * i0) >> 2;                  // i0 multiple of 8 -> exact
    for (int u = tid; u < 2304; u += 256) {   // 128 o x 18 f4
      int o = u / 18, r = u - o * 18;
      float4 v = s4[o * 288 + i0q + r];
      float* d = sbuf + o * 73 + r * 4;
      d[0] = v.x; d[1] = v.y; d[2] = v.z; d[3] = v.w;
    }
    __syncthreads();
#pragma unroll
    for (int k = 0; k < 4; ++k) {
      int idx = base + k * 256 + tid;
      int o = idx & 127, il = ((idx & 16383) >> 7) - i0;
      Wt[idx] = sbuf[o * 73 + il * 9 + tap];  // lanes: o-consecutive, 2-way banks
    }
  } else {
    // ---- wr1T transpose: LDS-tile (8 i per o) ----
    int blk_ = blk - 348;                     // 0..31
    int base = blk_ * 1024;
    int i0 = base >> 7;
    const float4* s4 = (const float4*)wr1;
    {
      int o = tid >> 1, r = tid & 1;          // 128 o x 2 f4
      float4 v = s4[o * 64 + (i0 >> 2) + r];
      float* d = sbuf + o * 9 + r * 4;
      d[0] = v.x; d[1] = v.y; d[2] = v.z; d[3] = v.w;
    }
    __syncthreads();
#pragma unroll
    for (int k = 0; k < 4; ++k) {
      int idx = base + k * 256 + tid;
      int o = idx & 127, il = (idx >> 7) - i0;
      wr1T[idx] = sbuf[o * 9 + il];
    }
  }
}

// ---------------- merged relational kernel (one block owns one q-row end-to-end;
// out fused; NO cross-block communication — no fences (a per-block
// __threadfence() election measured rel 91->196us, WRITE 0.6->3.4MB).
// blk 0..399   : main path, q in [200,400): TWO half-image passes, FULLY UNROLLED
//                (runtime `for half` loop made the compiler spill the MFMA
//                accumulator to scratch: WRITE_SIZE 0.6->29.6MB, rel 91->105us.
//                #pragma unroll restores straight-line per-pass codegen with
//                acc in AGPRs — keep it).
// blk 400..799 : const path, q in [0,200) (r1 spatially constant -> 9-pattern
//                shortcut), out row computed in-block.
// REGISTER BUDGET NOTE (R8 lesson): launch_bounds(512,4) + acc's 64 AGPRs leaves
// only ~64 arch VGPRs. Hoisting per-channel constants into register arrays in
// phase1 (32 regs) blew the budget -> 15MB of scratch spill, rel 94.5->96.5us.
// Keep phase1/epilogue in the register-lean re-read-from-LDS form. LDS reads
// are cheap; spills are not.
// L2 note: const blocks partially co-run with main; safe because their weight
// reads are the coalesced Wt/wr1T copies — hot set fits each XCD's 4MB L2.
__global__ __launch_bounds__(512, 4) void rel_kernel(
    const float* __restrict__ feat, const float* __restrict__ featT,
    const float* __restrict__ wr1T, const float* __restrict__ Pfx,
    const float* __restrict__ gr1, const float* __restrict__ br1,
    const float* __restrict__ mr1, const float* __restrict__ vr1,
    const unsigned short* __restrict__ Apack, const float* __restrict__ Wt,
    const float* __restrict__ gr2, const float* __restrict__ br2,
    const float* __restrict__ mr2, const float* __restrict__ vr2,
    const float* __restrict__ wr3,
    const float* __restrict__ gr3, const float* __restrict__ br3,
    const float* __restrict__ mr3, const float* __restrict__ vr3,
    const float* __restrict__ x, const float* __restrict__ w2,
    const float* __restrict__ g2, const float* __restrict__ b2,
    const float* __restrict__ m2, const float* __restrict__ v2,
    float* __restrict__ out) {

  __shared__ __align__(16) unsigned short r1f[16 * 221 * 8];   // 56576 B
  __shared__ float f0s[220], f1s[220], scoreS[208];
  __shared__ float wB0s[128], wB1s[128];
  __shared__ float sc1[128], sh1[128], sc2[128], sh2[128], w3c[128];
  __shared__ __align__(16) float attT[128];
  __shared__ __align__(16) float fA[256];
  __shared__ float r1c[128], AvS[128];
  __shared__ float vS[9 * 128];
  __shared__ float spS[9];
  __shared__ float spP[400];

  int tid = threadIdx.x, lane = tid & 63, wid = tid >> 6;
  int blk = blockIdx.x;

  if (tid < 128) {
    float s1 = gr1[tid] * rsqrtf(vr1[tid] + EPS); sc1[tid] = s1; sh1[tid] = br1[tid] - mr1[tid] * s1;
    float s2 = gr2[tid] * rsqrtf(vr2[tid] + EPS); sc2[tid] = s2; sh2[tid] = br2[tid] - mr2[tid] * s2;
    w3c[tid] = wr3[tid];
    attT[tid] = 0.f; AvS[tid] = 0.f;
  }
  float s3 = gr3[0] * rsqrtf(vr3[0] + EPS);
  float sh3 = br3[0] - mr3[0] * s3;

  if (blk < 400) {
    // ================= main path: one block = one q row, two half passes =========
    int b = blk / 200, q = 200 + blk % 200;
    int c0 = (q * 256) / 400, c1 = c0 + 1;
    if (tid < 128) {
      const float* Po = Pfx + tid * 257;
      int e0 = min(256, 400 * c0 + 400 - 256 * q);   // s0 is always 0
      wB0s[tid] = Po[e0];
      float wv = 0.f;
      if (c1 < 256) {
        int s1i = min(256, max(0, 400 * c1 - 256 * q));
        wv = Po[256] - Po[s1i];
      }
      wB1s[tid] = wv;
    }

    int wm = wid & 1, wn = wid >> 1;
    int ntcnt = (wn == 0) ? 4 : 3;
    int n16 = lane & 15, quad = lane >> 4;
    const char* wbase = (const char*)Apack + (size_t)((wm * 4) * 64 + lane) * 16;

#pragma unroll
    for (int half = 0; half < 2; ++half) {
      if (tid < 220) {
        int p = tid + 180 * half;
        f0s[tid] = featT[(b * 128 + (c0 - 128)) * 400 + p];                  // coalesced
        f1s[tid] = (c1 < 256) ? featT[(b * 128 + (c1 - 128)) * 400 + p] : 0.f;
      }
      if (tid < 208) scoreS[tid] = 0.f;
      __syncthreads();

      // phase1: r1 = SiLU(BN(wB0*f0 + wB1*f1)) -> LDS bf16 fragment-major
      // (register-lean form: re-read per-channel constants from LDS each item)
      for (int i = tid; i < 3520; i += 512) {
        int plane = i / 220, p = i - plane * 220;
        int cb = (plane >> 2) * 32 + (plane & 3) * 8;
        float fa0 = f0s[p], fa1 = f1s[p];
        unsigned int pk[4];
#pragma unroll
        for (int jp = 0; jp < 4; ++jp) {
          int c = cb + jp * 2;
          float y0 = wB0s[c] * fa0 + wB1s[c] * fa1;     y0 = y0 * sc1[c] + sh1[c];
          float y1 = wB0s[c + 1] * fa0 + wB1s[c + 1] * fa1; y1 = y1 * sc1[c + 1] + sh1[c + 1];
          pk[jp] = pack_bf16(silu(y0), silu(y1));
        }
        *(uint4*)&r1f[(plane * 221 + p) * 8] = make_uint4(pk[0], pk[1], pk[2], pk[3]);
      }
      if (tid < 16) *(uint4*)&r1f[(tid * 221 + 220) * 8] = make_uint4(0, 0, 0, 0);

      int hA[4], wA[4], poA[4]; bool pov[4];
#pragma unroll
      for (int t = 0; t < 4; ++t) {
        int po = (wn + 4 * t) * 16 + n16;
        poA[t] = po; pov[t] = po < 200;
        int pg = half * 200 + po;
        hA[t] = pg / 20; wA[t] = pg - 20 * hA[t];
      }
      f32x4 acc[4][4];
#pragma unroll
      for (int mt = 0; mt < 4; ++mt)
#pragma unroll
        for (int t = 0; t < 4; ++t) acc[mt][t] = f32x4{0.f, 0.f, 0.f, 0.f};

      __syncthreads();   // r1f visible — NO barriers through the K-loop

      for (int tap = 0; tap < 9; ++tap) {
        int dy = tap / 3 - 1, dx = tap % 3 - 1;
        int pp[4];
#pragma unroll
        for (int t = 0; t < 4; ++t) {
          int hh = hA[t] + dy, ww = wA[t] + dx;
          bool valid = pov[t] & (hh >= 0) & (hh < 20) & (ww >= 0) & (ww < 20);
          pp[t] = valid ? (hh - 9 * half) * 20 + ww : 220;
        }
#pragma unroll
        for (int ks = 0; ks < 4; ++ks) {
          const char* wp = wbase + (size_t)(tap * 4 + ks) * 8192;
          bf16x8 af0 = *(const bf16x8*)(wp);
          bf16x8 af1 = *(const bf16x8*)(wp + 1024);
          bf16x8 af2 = *(const bf16x8*)(wp + 2048);
          bf16x8 af3 = *(const bf16x8*)(wp + 3072);
          int pbase = (ks * 4 + quad) * 221;
#pragma unroll
          for (int t = 0; t < 4; ++t) {
            if (t < ntcnt) {                 // wave-uniform
              bf16x8 bfr = *(const bf16x8*)&r1f[(pbase + pp[t]) * 8];
              acc[0][t] = __builtin_amdgcn_mfma_f32_16x16x32_bf16(af0, bfr, acc[0][t], 0, 0, 0);
              acc[1][t] = __builtin_amdgcn_mfma_f32_16x16x32_bf16(af1, bfr, acc[1][t], 0, 0, 0);
              acc[2][t] = __builtin_amdgcn_mfma_f32_16x16x32_bf16(af2, bfr, acc[2][t], 0, 0, 0);
              acc[3][t] = __builtin_amdgcn_mfma_f32_16x16x32_bf16(af3, bfr, acc[3][t], 0, 0, 0);
            }
          }
        }
      }

      // epilogue: BN2+SiLU, conv3 dot, reduce to scoreS (register-lean form)
#pragma unroll
      for (int t = 0; t < 4; ++t) {
        if (t < ntcnt) {
          float ps = 0.f;
#pragma unroll
          for (int mt = 0; mt < 4; ++mt) {
#pragma unroll
            for (int r = 0; r < 4; ++r) {
              int o = wm * 64 + mt * 16 + quad * 4 + r;
              float y = acc[mt][t][r] * sc2[o] + sh2[o];
              ps += silu(y) * w3c[o];
            }
          }
          ps += __shfl_xor(ps, 16);
          ps += __shfl_xor(ps, 32);
          if (quad == 0 && pov[t]) atomicAdd(&scoreS[poA[t]], ps);
        }
      }
      __syncthreads();

      if (tid < 200) scoreS[tid] = silu(scoreS[tid] * s3 + sh3);
      __syncthreads();

      {
        int c = tid & 127, part = tid >> 7;
        float s = 0.f;
        int j0 = part * 50;
        const float* fb = feat + ((size_t)(b * 400 + half * 200 + j0)) * 128 + c;
#pragma unroll 10
        for (int j = 0; j < 50; ++j)
          s += scoreS[j0 + j] * fb[(size_t)j * 128];
        atomicAdd(&attT[c], s);
      }
      __syncthreads();   // attT pass done; also guards scoreS/f0s/r1f reuse next pass
    }

    // fused out: att row complete in LDS
    {
      int c = tid >> 2, sub = tid & 3;
      const float4* w4 = (const float4*)(w2 + c * 128 + sub * 32);
      const float4* v4 = (const float4*)(attT + sub * 32);
      float s0 = 0.f, s1 = 0.f, s2v = 0.f, s3v = 0.f;
#pragma unroll
      for (int i = 0; i < 8; ++i) {
        float4 wv = w4[i], xx = v4[i];
        s0 += wv.x * xx.x; s1 += wv.y * xx.y; s2v += wv.z * xx.z; s3v += wv.w * xx.w;
      }
      float s = (s0 + s1) + (s2v + s3v);
      s += __shfl_xor(s, 1);
      s += __shfl_xor(s, 2);
      if (sub == 0) {
        float scc = g2[c] * rsqrtf(v2[c] + EPS);
        float y = s * scc + (b2[c] - m2[c] * scc);
        int xi = (b * 128 + c) * 400 + q;
        out[xi] = silu(y) + x[xi];
      }
    }
  } else {
    // ================= const path (q < 200): r1 constant over pixels =================
    int cidx = blk - 400;
    int b = cidx / 200, q = cidx % 200;
    if (tid < 256) {
      int u = q * 256 + tid; int c = u / 400, i2 = u - c * 400;
      fA[tid] = featT[(b * 128 + c) * 400 + i2];           // coalesced
    }
    for (int k = tid; k < 1152; k += 512) vS[k] = 0.f;
    __syncthreads();
    {
      int o = tid & 127, part = tid >> 7;
      const float* wt = wr1T + part * 64 * 128 + o;        // coalesced across o
      const float* fv = fA + part * 64;
      float a = 0.f;
#pragma unroll 8
      for (int k = 0; k < 64; ++k) a += wt[k * 128] * fv[k];
      atomicAdd(&AvS[o], a);
    }
    __syncthreads();
    if (tid < 128) r1c[tid] = silu(AvS[tid] * sc1[tid] + sh1[tid]);
    __syncthreads();
    {
      int o = tid & 127, part = tid >> 7;
      const float* rc = r1c + part * 32;
      for (int tap = 0; tap < 9; ++tap) {
        const float* wt = Wt + tap * 16384 + part * 32 * 128 + o;
        float s = 0.f;
#pragma unroll 8
        for (int i2 = 0; i2 < 32; ++i2) s += wt[i2 * 128] * rc[i2];
        atomicAdd(&vS[tap * 128 + o], s);
      }
    }
    __syncthreads();
    for (int pat = wid; pat < 9; pat += 8) {
      int ry = pat / 3, rx = pat % 3;
      float ps = 0.f;
      for (int oo = lane; oo < 128; oo += 64) {
        float y = 0.f;
#pragma unroll
        for (int dy = -1; dy <= 1; ++dy) {
          if ((ry == 0 && dy < 0) || (ry == 2 && dy > 0)) continue;
#pragma unroll
          for (int dx = -1; dx <= 1; ++dx) {
            if ((rx == 0 && dx < 0) || (rx == 2 && dx > 0)) continue;
            y += vS[((dy + 1) * 3 + (dx + 1)) * 128 + oo];
          }
        }
        y = y * sc2[oo] + sh2[oo];
        ps += silu(y) * w3c[oo];
      }
#pragma unroll
      for (int sft = 32; sft >= 1; sft >>= 1) ps += __shfl_xor(ps, sft);
      if (lane == 0) spS[pat] = silu(ps * s3 + sh3);
    }
    __syncthreads();

    for (int p = tid; p < 400; p += 512) {
      int r = p / 20, cm = p - 20 * r;
      int ry = (r == 0) ? 0 : (r == 19) ? 2 : 1;
      int rx = (cm == 0) ? 0 : (cm == 19) ? 2 : 1;
      spP[p] = spS[ry * 3 + rx];
    }
    __syncthreads();
    {
      int c = tid & 127, part = tid >> 7;
      const float* fb = feat + ((size_t)(b * 400) + part * 100) * 128 + c;
      const float* sp = spP + part * 100;
      float s = 0.f;
#pragma unroll 10
      for (int j = 0; j < 100; ++j) s += sp[j] * fb[(size_t)j * 128];
      atomicAdd(&attT[c], s);
    }
    __syncthreads();
    // fused out: att row complete in LDS (attT); global att never touched
    {
      int c = tid >> 2, sub = tid & 3;
      const float4* w4 = (const float4*)(w2 + c * 128 + sub * 32);
      const float4* v4 = (const float4*)(attT + sub * 32);
      float s0 = 0.f, s1 = 0.f, s2v = 0.f, s3v = 0.f;
#pragma unroll
      for (int i = 0; i < 8; ++i) {
        float4 wv = w4[i], xx = v4[i];
        s0 += wv.x * xx.x; s1 += wv.y * xx.y; s2v += wv.z * xx.z; s3v += wv.w * xx.w;
      }
      float s = (s0 + s1) + (s2v + s3v);
      s += __shfl_xor(s, 1);
      s += __shfl_xor(s, 2);
      if (sub == 0) {
        float scc = g2[c] * rsqrtf(v2[c] + EPS);
        float y = s * scc + (b2[c] - m2[c] * scc);
        int xi = (b * 128 + c) * 400 + q;
        out[xi] = silu(y) + x[xi];
      }
    }
  }
}

extern "C" void kernel_launch(void* const* d_in, const int* in_sizes, int n_in,
                              void* d_out, int out_size, void* d_ws, size_t ws_size,
                              hipStream_t stream) {
  const float* x   = (const float*)d_in[0];
  const float* w1  = (const float*)d_in[1];
  const float* g1  = (const float*)d_in[2];
  const float* b1  = (const float*)d_in[3];
  const float* m1  = (const float*)d_in[4];
  const float* v1  = (const float*)d_in[5];
  const float* w2  = (const float*)d_in[6];
  const float* g2  = (const float*)d_in[7];
  const float* b2  = (const float*)d_in[8];
  const float* m2  = (const float*)d_in[9];
  const float* v2  = (const float*)d_in[10];
  const float* wr1 = (const float*)d_in[11];
  const float* gr1 = (const float*)d_in[12];
  const float* br1 = (const float*)d_in[13];
  const float* mr1 = (const float*)d_in[14];
  const float* vr1 = (const float*)d_in[15];
  const float* wr2 = (const float*)d_in[16];
  const float* gr2 = (const float*)d_in[17];
  const float* br2 = (const float*)d_in[18];
  const float* mr2 = (const float*)d_in[19];
  const float* vr2 = (const float*)d_in[20];
  const float* wr3 = (const float*)d_in[21];
  const float* gr3 = (const float*)d_in[22];
  const float* br3 = (const float*)d_in[23];
  const float* mr3 = (const float*)d_in[24];
  const float* vr3 = (const float*)d_in[25];
  float* out = (float*)d_out;

  char* ws = (char*)d_ws;
  float*          feat  = (float*)ws;                        // 409600 B
  unsigned short* Apack = (unsigned short*)(ws + 819200);    // 294912 B
  float*          Pfx   = (float*)(ws + 1114112);            // 131584 B
  float*          Wt    = (float*)(ws + 1245696);            // 589824 B
  float*          featT = (float*)(ws + 1901056);            // 409600 B
  float*          wr1T  = (float*)(ws + 2310656);            // 131072 B

  prep_kernel<<<380, 256, 0, stream>>>(x, w1, g1, b1, m1, v1, wr2, wr1,
                                       feat, featT, Apack, Pfx, Wt, wr1T);
  rel_kernel<<<800, 512, 0, stream>>>(feat, featT, wr1T, Pfx, gr1, br1, mr1, vr1,
                                      Apack, Wt,
                                      gr2, br2, mr2, vr2, wr3, gr3, br3, mr3, vr3,
                                      x, w2, g2, b2, m2, v2, out);
}

// Round 10
// 192.299 us; speedup vs baseline: 1.0095x; 1.0013x over previous
//
#include <hip/hip_runtime.h>

#define EPS 1e-5f

typedef __bf16 bf16x8 __attribute__((ext_vector_type(8)));
typedef float  f32x4  __attribute__((ext_vector_type(4)));

// manual RNE bf16 round: used in rel phase1 — measured FASTER there than the
// native-cast cvt_pk form (R9: rel 94.5->98.1us with casts; scheduling effect).
__device__ __forceinline__ unsigned short f2bf(float f) {
  unsigned int u = __float_as_uint(f);
  unsigned int r = (u + 0x7fffu + ((u >> 16) & 1u)) >> 16;
  return (unsigned short)r;
}
// native-cast RNE bf16: used in prep only (same bits; coincided with ~4us
// non-rel gain in R9, zero register cost).
__device__ __forceinline__ unsigned short f2bfn(float f) {
  return __builtin_bit_cast(unsigned short, (__bf16)f);
}
// silu via v_rcp_f32 (avoids precise-div sequence; ~2^-22 rel err, fine at bf16 tol)
__device__ __forceinline__ float silu(float y) {
  return y * __builtin_amdgcn_rcpf(1.f + __expf(-y));
}

// ---------------- prep: ALL weight/activation reads coalesced via per-block LDS
// tiles, kept WIDE (380 parallel blocks — do NOT re-serialize into few blocks:
// a 5-block LDS-tiled prep measured ~16us WORSE by sitting alone on the critical
// path). Per-lane strided gathers (64 cachelines per wave-load) measured
// ~18-20us for the transpose paths alone (R1 vs R2 non-rel A/B).
// blk 0..99    : feat/featT = SiLU(BN(conv1x1(x,w1))), 8 px/block; w1 staged in
//                LDS [128][129] (pad -> 2-way banks = free), exact s0..s3 numerics
// blk 100..171 : pack wr2 -> MFMA A-frag bf16 (frag f = tap*32+ks*8+m8), LDS-tiled
// blk 172..203 : wave-parallel prefix sums of wr1 rows -> Pfx[o][0..256]
// blk 204..347 : transpose wr2 -> Wt[tap][i][o] fp32, LDS-tiled
// blk 348..379 : transpose wr1 -> wr1T[i][o] fp32, LDS-tiled
// NOTE: Wt/wr1T transposed workspace copies are LOAD-BEARING for rel's const
// path (coalesced reads; raw wr1/wr2 reads in rel thrash L2 and evict Apack —
// measured FETCH 7MB->180MB, rel 91->259us). Do not "simplify" away.
__global__ void prep_kernel(const float* __restrict__ x, const float* __restrict__ w1,
                            const float* __restrict__ g1, const float* __restrict__ b1,
                            const float* __restrict__ m1, const float* __restrict__ v1,
                            const float* __restrict__ wr2, const float* __restrict__ wr1,
                            float* __restrict__ feat, float* __restrict__ featT,
                            unsigned short* __restrict__ Apack, float* __restrict__ Pfx,
                            float* __restrict__ Wt, float* __restrict__ wr1T) {
  __shared__ __align__(16) float sbuf[18496];   // 73984 B, unioned across paths
  int blk = blockIdx.x;
  int tid = threadIdx.x;
  if (blk < 100) {
    // ---- feat: 8 px per block, w1 LDS-staged ----
    float* w1s = sbuf;               // [128][129]
    float* xvb = sbuf + 16512;       // [8][128]
    int p0 = blk * 8;
    int b = p0 / 400, pb = p0 % 400;   // 8 | 400 -> no b straddle
    const float4* w14 = (const float4*)w1;
    for (int u = tid; u < 4096; u += 256) {        // coalesced f4 reads of w1
      float4 v = w14[u];
      int c = u >> 5, i4 = (u & 31) * 4;
      float* d = w1s + c * 129 + i4;
      d[0] = v.x; d[1] = v.y; d[2] = v.z; d[3] = v.w;
    }
    for (int u = tid; u < 1024; u += 256) {        // x columns (unavoidable gather)
      int pl = u >> 7, c = u & 127;
      xvb[pl * 128 + c] = x[(b * 128 + c) * 400 + pb + pl];
    }
    __syncthreads();
    int c = tid & 127, pg = tid >> 7;
    float a0[4], a1[4], a2[4], a3[4];
#pragma unroll
    for (int q = 0; q < 4; ++q) { a0[q] = a1[q] = a2[q] = a3[q] = 0.f; }
    const float* wr = w1s + c * 129;
#pragma unroll 8
    for (int k = 0; k < 32; ++k) {
      float w0 = wr[4 * k], w1v = wr[4 * k + 1], w2v = wr[4 * k + 2], w3v = wr[4 * k + 3];
#pragma unroll
      for (int q = 0; q < 4; ++q) {
        float4 xx = *(const float4*)&xvb[(pg * 4 + q) * 128 + 4 * k];
        a0[q] += w0 * xx.x; a1[q] += w1v * xx.y; a2[q] += w2v * xx.z; a3[q] += w3v * xx.w;
      }
    }
    float sc = g1[c] * rsqrtf(v1[c] + EPS);
    float sh = b1[c] - m1[c] * sc;
#pragma unroll
    for (int q = 0; q < 4; ++q) {
      float s = (a0[q] + a1[q]) + (a2[q] + a3[q]);   // exact original grouping
      float f = silu(s * sc + sh);
      int p = pb + pg * 4 + q;
      feat[(b * 400 + p) * 128 + c] = f;     // coalesced
      featT[(b * 128 + c) * 400 + p] = f;    // scatter (layout needed by rel)
    }
  } else if (blk < 172) {
    // ---- Apack: LDS-tile the wr2 slice, emit bf16 frags ----
    int w_ = blk - 100;                       // 0..71
    int tap = w_ >> 3, ks = (w_ >> 1) & 3, o0 = (w_ & 1) * 64;
    const float4* s4 = (const float4*)wr2;
    for (int u = tid; u < 4608; u += 256) {   // 64 o x 72 f4, coalesced per row-chunk
      int o = u / 72, r = u - o * 72;
      float4 v = s4[(size_t)(o0 + o) * 288 + 72 * ks + r];
      float* d = sbuf + o * 289 + r * 4;
      d[0] = v.x; d[1] = v.y; d[2] = v.z; d[3] = v.w;
    }
    __syncthreads();
    int wv = tid >> 6, lane = tid & 63;
    int f = w_ * 4 + wv;
    int o_l = wv * 16 + (lane & 15);
    int ib = (lane >> 4) * 8;
    unsigned short* dst = Apack + ((size_t)f * 64 + lane) * 8;
#pragma unroll
    for (int j = 0; j < 8; ++j)
      dst[j] = f2bfn(sbuf[o_l * 289 + (ib + j) * 9 + tap]);
  } else if (blk < 204) {
    // ---- Pfx: prefix sums of wr1 rows (reads already coalesced f4) ----
    int o = (blk - 172) * 4 + (tid >> 6);
    int lane = tid & 63;
    float4 wv = ((const float4*)(wr1 + o * 256))[lane];
    float p0 = wv.x, p1 = p0 + wv.y, p2 = p1 + wv.z, p3 = p2 + wv.w;
    float v = p3;
#pragma unroll
    for (int d = 1; d < 64; d <<= 1) {
      float t = __shfl_up(v, d);
      if (lane >= d) v += t;
    }
    float off = v - p3;
    float* Po = Pfx + o * 257;
    if (lane == 0) Po[0] = 0.f;
    Po[lane * 4 + 1] = off + p0;
    Po[lane * 4 + 2] = off + p1;
    Po[lane * 4 + 3] = off + p2;
    Po[lane * 4 + 4] = off + p3;
  } else if (blk < 348) {
    // ---- Wt transpose: LDS-tile (8 i x 9 tap per o), coalesced both sides ----
    int blk_ = blk - 204;                     // 0..143
    int base = blk_ * 1024;
    int tap = blk_ >> 4;                      // 16 blocks per tap, no straddle
    int i0 = (blk_ & 15) * 8;
    const float4* s4 = (const float4*)wr2;
    int i0q = (9 * i0) >> 2;                  // i0 multiple of 8 -> exact
    for (int u = tid; u < 2304; u += 256) {   // 128 o x 18 f4
      int o = u / 18, r = u - o * 18;
      float4 v = s4[o * 288 + i0q + r];
      float* d = sbuf + o * 73 + r * 4;
      d[0] = v.x; d[1] = v.y; d[2] = v.z; d[3] = v.w;
    }
    __syncthreads();
#pragma unroll
    for (int k = 0; k < 4; ++k) {
      int idx = base + k * 256 + tid;
      int o = idx & 127, il = ((idx & 16383) >> 7) - i0;
      Wt[idx] = sbuf[o * 73 + il * 9 + tap];  // lanes: o-consecutive, 2-way banks
    }
  } else {
    // ---- wr1T transpose: LDS-tile (8 i per o) ----
    int blk_ = blk - 348;                     // 0..31
    int base = blk_ * 1024;
    int i0 = base >> 7;
    const float4* s4 = (const float4*)wr1;
    {
      int o = tid >> 1, r = tid & 1;          // 128 o x 2 f4
      float4 v = s4[o * 64 + (i0 >> 2) + r];
      float* d = sbuf + o * 9 + r * 4;
      d[0] = v.x; d[1] = v.y; d[2] = v.z; d[3] = v.w;
    }
    __syncthreads();
#pragma unroll
    for (int k = 0; k < 4; ++k) {
      int idx = base + k * 256 + tid;
      int o = idx & 127, il = (idx >> 7) - i0;
      wr1T[idx] = sbuf[o * 9 + il];
    }
  }
}

// ---------------- merged relational kernel (one block owns one q-row end-to-end;
// out fused; NO cross-block communication — no fences (a per-block
// __threadfence() election measured rel 91->196us, WRITE 0.6->3.4MB).
// blk 0..399   : main path, q in [200,400): TWO half-image passes, FULLY UNROLLED
//                (runtime `for half` loop made the compiler spill the MFMA
//                accumulator to scratch: WRITE_SIZE 0.6->29.6MB, rel 91->105us.
//                #pragma unroll restores straight-line per-pass codegen with
//                acc in AGPRs — keep it).
// blk 400..799 : const path, q in [0,200) (r1 spatially constant -> 9-pattern
//                shortcut), out row computed in-block.
// REGISTER BUDGET NOTE (R8 lesson): launch_bounds(512,4) + acc's 64 AGPRs leaves
// only ~64 arch VGPRs. Hoisting per-channel constants into register arrays in
// phase1 (32 regs) blew the budget -> 15MB of scratch spill, rel 94.5->96.5us.
// Keep phase1/epilogue in the register-lean re-read-from-LDS form.
// PACK NOTE (R9 lesson): native-cast bf16 pair-pack in phase1 measured SLOWER
// (rel 94.5->98.1us, no spill — scheduling effect). Keep the manual f2bf here.
// L2 note: const blocks partially co-run with main; safe because their weight
// reads are the coalesced Wt/wr1T copies — hot set fits each XCD's 4MB L2.
__global__ __launch_bounds__(512, 4) void rel_kernel(
    const float* __restrict__ feat, const float* __restrict__ featT,
    const float* __restrict__ wr1T, const float* __restrict__ Pfx,
    const float* __restrict__ gr1, const float* __restrict__ br1,
    const float* __restrict__ mr1, const float* __restrict__ vr1,
    const unsigned short* __restrict__ Apack, const float* __restrict__ Wt,
    const float* __restrict__ gr2, const float* __restrict__ br2,
    const float* __restrict__ mr2, const float* __restrict__ vr2,
    const float* __restrict__ wr3,
    const float* __restrict__ gr3, const float* __restrict__ br3,
    const float* __restrict__ mr3, const float* __restrict__ vr3,
    const float* __restrict__ x, const float* __restrict__ w2,
    const float* __restrict__ g2, const float* __restrict__ b2,
    const float* __restrict__ m2, const float* __restrict__ v2,
    float* __restrict__ out) {

  __shared__ __align__(16) unsigned short r1f[16 * 221 * 8];   // 56576 B
  __shared__ float f0s[220], f1s[220], scoreS[208];
  __shared__ float wB0s[128], wB1s[128];
  __shared__ float sc1[128], sh1[128], sc2[128], sh2[128], w3c[128];
  __shared__ __align__(16) float attT[128];
  __shared__ __align__(16) float fA[256];
  __shared__ float r1c[128], AvS[128];
  __shared__ float vS[9 * 128];
  __shared__ float spS[9];
  __shared__ float spP[400];

  int tid = threadIdx.x, lane = tid & 63, wid = tid >> 6;
  int blk = blockIdx.x;

  if (tid < 128) {
    float s1 = gr1[tid] * rsqrtf(vr1[tid] + EPS); sc1[tid] = s1; sh1[tid] = br1[tid] - mr1[tid] * s1;
    float s2 = gr2[tid] * rsqrtf(vr2[tid] + EPS); sc2[tid] = s2; sh2[tid] = br2[tid] - mr2[tid] * s2;
    w3c[tid] = wr3[tid];
    attT[tid] = 0.f; AvS[tid] = 0.f;
  }
  float s3 = gr3[0] * rsqrtf(vr3[0] + EPS);
  float sh3 = br3[0] - mr3[0] * s3;

  if (blk < 400) {
    // ================= main path: one block = one q row, two half passes =========
    int b = blk / 200, q = 200 + blk % 200;
    int c0 = (q * 256) / 400, c1 = c0 + 1;
    if (tid < 128) {
      const float* Po = Pfx + tid * 257;
      int e0 = min(256, 400 * c0 + 400 - 256 * q);   // s0 is always 0
      wB0s[tid] = Po[e0];
      float wv = 0.f;
      if (c1 < 256) {
        int s1i = min(256, max(0, 400 * c1 - 256 * q));
        wv = Po[256] - Po[s1i];
      }
      wB1s[tid] = wv;
    }

    int wm = wid & 1, wn = wid >> 1;
    int ntcnt = (wn == 0) ? 4 : 3;
    int n16 = lane & 15, quad = lane >> 4;
    const char* wbase = (const char*)Apack + (size_t)((wm * 4) * 64 + lane) * 16;

#pragma unroll
    for (int half = 0; half < 2; ++half) {
      if (tid < 220) {
        int p = tid + 180 * half;
        f0s[tid] = featT[(b * 128 + (c0 - 128)) * 400 + p];                  // coalesced
        f1s[tid] = (c1 < 256) ? featT[(b * 128 + (c1 - 128)) * 400 + p] : 0.f;
      }
      if (tid < 208) scoreS[tid] = 0.f;
      __syncthreads();

      // phase1: r1 = SiLU(BN(wB0*f0 + wB1*f1)) -> LDS bf16 fragment-major
      for (int i = tid; i < 3520; i += 512) {
        int plane = i / 220, p = i - plane * 220;
        int cb = (plane >> 2) * 32 + (plane & 3) * 8;
        float fa0 = f0s[p], fa1 = f1s[p];
        unsigned int pk[4];
#pragma unroll
        for (int jp = 0; jp < 4; ++jp) {
          int c = cb + jp * 2;
          float y0 = wB0s[c] * fa0 + wB1s[c] * fa1;     y0 = y0 * sc1[c] + sh1[c];
          float y1 = wB0s[c + 1] * fa0 + wB1s[c + 1] * fa1; y1 = y1 * sc1[c + 1] + sh1[c + 1];
          pk[jp] = (unsigned int)f2bf(silu(y0)) | ((unsigned int)f2bf(silu(y1)) << 16);
        }
        *(uint4*)&r1f[(plane * 221 + p) * 8] = make_uint4(pk[0], pk[1], pk[2], pk[3]);
      }
      if (tid < 16) *(uint4*)&r1f[(tid * 221 + 220) * 8] = make_uint4(0, 0, 0, 0);

      int hA[4], wA[4], poA[4]; bool pov[4];
#pragma unroll
      for (int t = 0; t < 4; ++t) {
        int po = (wn + 4 * t) * 16 + n16;
        poA[t] = po; pov[t] = po < 200;
        int pg = half * 200 + po;
        hA[t] = pg / 20; wA[t] = pg - 20 * hA[t];
      }
      f32x4 acc[4][4];
#pragma unroll
      for (int mt = 0; mt < 4; ++mt)
#pragma unroll
        for (int t = 0; t < 4; ++t) acc[mt][t] = f32x4{0.f, 0.f, 0.f, 0.f};

      __syncthreads();   // r1f visible — NO barriers through the K-loop

      for (int tap = 0; tap < 9; ++tap) {
        int dy = tap / 3 - 1, dx = tap % 3 - 1;
        int pp[4];
#pragma unroll
        for (int t = 0; t < 4; ++t) {
          int hh = hA[t] + dy, ww = wA[t] + dx;
          bool valid = pov[t] & (hh >= 0) & (hh < 20) & (ww >= 0) & (ww < 20);
          pp[t] = valid ? (hh - 9 * half) * 20 + ww : 220;
        }
#pragma unroll
        for (int ks = 0; ks < 4; ++ks) {
          const char* wp = wbase + (size_t)(tap * 4 + ks) * 8192;
          bf16x8 af0 = *(const bf16x8*)(wp);
          bf16x8 af1 = *(const bf16x8*)(wp + 1024);
          bf16x8 af2 = *(const bf16x8*)(wp + 2048);
          bf16x8 af3 = *(const bf16x8*)(wp + 3072);
          int pbase = (ks * 4 + quad) * 221;
#pragma unroll
          for (int t = 0; t < 4; ++t) {
            if (t < ntcnt) {                 // wave-uniform
              bf16x8 bfr = *(const bf16x8*)&r1f[(pbase + pp[t]) * 8];
              acc[0][t] = __builtin_amdgcn_mfma_f32_16x16x32_bf16(af0, bfr, acc[0][t], 0, 0, 0);
              acc[1][t] = __builtin_amdgcn_mfma_f32_16x16x32_bf16(af1, bfr, acc[1][t], 0, 0, 0);
              acc[2][t] = __builtin_amdgcn_mfma_f32_16x16x32_bf16(af2, bfr, acc[2][t], 0, 0, 0);
              acc[3][t] = __builtin_amdgcn_mfma_f32_16x16x32_bf16(af3, bfr, acc[3][t], 0, 0, 0);
            }
          }
        }
      }

      // epilogue: BN2+SiLU, conv3 dot, reduce to scoreS
#pragma unroll
      for (int t = 0; t < 4; ++t) {
        if (t < ntcnt) {
          float ps = 0.f;
#pragma unroll
          for (int mt = 0; mt < 4; ++mt) {
#pragma unroll
            for (int r = 0; r < 4; ++r) {
              int o = wm * 64 + mt * 16 + quad * 4 + r;
              float y = acc[mt][t][r] * sc2[o] + sh2[o];
              ps += silu(y) * w3c[o];
            }
          }
          ps += __shfl_xor(ps, 16);
          ps += __shfl_xor(ps, 32);
          if (quad == 0 && pov[t]) atomicAdd(&scoreS[poA[t]], ps);
        }
      }
      __syncthreads();

      if (tid < 200) scoreS[tid] = silu(scoreS[tid] * s3 + sh3);
      __syncthreads();

      {
        int c = tid & 127, part = tid >> 7;
        float s = 0.f;
        int j0 = part * 50;
        const float* fb = feat + ((size_t)(b * 400 + half * 200 + j0)) * 128 + c;
#pragma unroll 10
        for (int j = 0; j < 50; ++j)
          s += scoreS[j0 + j] * fb[(size_t)j * 128];
        atomicAdd(&attT[c], s);
      }
      __syncthreads();   // attT pass done; also guards scoreS/f0s/r1f reuse next pass
    }

    // fused out: att row complete in LDS
    {
      int c = tid >> 2, sub = tid & 3;
      const float4* w4 = (const float4*)(w2 + c * 128 + sub * 32);
      const float4* v4 = (const float4*)(attT + sub * 32);
      float s0 = 0.f, s1 = 0.f, s2v = 0.f, s3v = 0.f;
#pragma unroll
      for (int i = 0; i < 8; ++i) {
        float4 wv = w4[i], xx = v4[i];
        s0 += wv.x * xx.x; s1 += wv.y * xx.y; s2v += wv.z * xx.z; s3v += wv.w * xx.w;
      }
      float s = (s0 + s1) + (s2v + s3v);
      s += __shfl_xor(s, 1);
      s += __shfl_xor(s, 2);
      if (sub == 0) {
        float scc = g2[c] * rsqrtf(v2[c] + EPS);
        float y = s * scc + (b2[c] - m2[c] * scc);
        int xi = (b * 128 + c) * 400 + q;
        out[xi] = silu(y) + x[xi];
      }
    }
  } else {
    // ================= const path (q < 200): r1 constant over pixels =================
    int cidx = blk - 400;
    int b = cidx / 200, q = cidx % 200;
    if (tid < 256) {
      int u = q * 256 + tid; int c = u / 400, i2 = u - c * 400;
      fA[tid] = featT[(b * 128 + c) * 400 + i2];           // coalesced
    }
    for (int k = tid; k < 1152; k += 512) vS[k] = 0.f;
    __syncthreads();
    {
      int o = tid & 127, part = tid >> 7;
      const float* wt = wr1T + part * 64 * 128 + o;        // coalesced across o
      const float* fv = fA + part * 64;
      float a = 0.f;
#pragma unroll 8
      for (int k = 0; k < 64; ++k) a += wt[k * 128] * fv[k];
      atomicAdd(&AvS[o], a);
    }
    __syncthreads();
    if (tid < 128) r1c[tid] = silu(AvS[tid] * sc1[tid] + sh1[tid]);
    __syncthreads();
    {
      int o = tid & 127, part = tid >> 7;
      const float* rc = r1c + part * 32;
      for (int tap = 0; tap < 9; ++tap) {
        const float* wt = Wt + tap * 16384 + part * 32 * 128 + o;
        float s = 0.f;
#pragma unroll 8
        for (int i2 = 0; i2 < 32; ++i2) s += wt[i2 * 128] * rc[i2];
        atomicAdd(&vS[tap * 128 + o], s);
      }
    }
    __syncthreads();
    for (int pat = wid; pat < 9; pat += 8) {
      int ry = pat / 3, rx = pat % 3;
      float ps = 0.f;
      for (int oo = lane; oo < 128; oo += 64) {
        float y = 0.f;
#pragma unroll
        for (int dy = -1; dy <= 1; ++dy) {
          if ((ry == 0 && dy < 0) || (ry == 2 && dy > 0)) continue;
#pragma unroll
          for (int dx = -1; dx <= 1; ++dx) {
            if ((rx == 0 && dx < 0) || (rx == 2 && dx > 0)) continue;
            y += vS[((dy + 1) * 3 + (dx + 1)) * 128 + oo];
          }
        }
        y = y * sc2[oo] + sh2[oo];
        ps += silu(y) * w3c[oo];
      }
#pragma unroll
      for (int sft = 32; sft >= 1; sft >>= 1) ps += __shfl_xor(ps, sft);
      if (lane == 0) spS[pat] = silu(ps * s3 + sh3);
    }
    __syncthreads();

    for (int p = tid; p < 400; p += 512) {
      int r = p / 20, cm = p - 20 * r;
      int ry = (r == 0) ? 0 : (r == 19) ? 2 : 1;
      int rx = (cm == 0) ? 0 : (cm == 19) ? 2 : 1;
      spP[p] = spS[ry * 3 + rx];
    }
    __syncthreads();
    {
      int c = tid & 127, part = tid >> 7;
      const float* fb = feat + ((size_t)(b * 400) + part * 100) * 128 + c;
      const float* sp = spP + part * 100;
      float s = 0.f;
#pragma unroll 10
      for (int j = 0; j < 100; ++j) s += sp[j] * fb[(size_t)j * 128];
      atomicAdd(&attT[c], s);
    }
    __syncthreads();
    // fused out: att row complete in LDS (attT); global att never touched
    {
      int c = tid >> 2, sub = tid & 3;
      const float4* w4 = (const float4*)(w2 + c * 128 + sub * 32);
      const float4* v4 = (const float4*)(attT + sub * 32);
      float s0 = 0.f, s1 = 0.f, s2v = 0.f, s3v = 0.f;
#pragma unroll
      for (int i = 0; i < 8; ++i) {
        float4 wv = w4[i], xx = v4[i];
        s0 += wv.x * xx.x; s1 += wv.y * xx.y; s2v += wv.z * xx.z; s3v += wv.w * xx.w;
      }
      float s = (s0 + s1) + (s2v + s3v);
      s += __shfl_xor(s, 1);
      s += __shfl_xor(s, 2);
      if (sub == 0) {
        float scc = g2[c] * rsqrtf(v2[c] + EPS);
        float y = s * scc + (b2[c] - m2[c] * scc);
        int xi = (b * 128 + c) * 400 + q;
        out[xi] = silu(y) + x[xi];
      }
    }
  }
}

extern "C" void kernel_launch(void* const* d_in, const int* in_sizes, int n_in,
                              void* d_out, int out_size, void* d_ws, size_t ws_size,
                              hipStream_t stream) {
  const float* x   = (const float*)d_in[0];
  const float* w1  = (const float*)d_in[1];
  const float* g1  = (const float*)d_in[2];
  const float* b1  = (const float*)d_in[3];
  const float* m1  = (const float*)d_in[4];
  const float* v1  = (const float*)d_in[5];
  const float* w2  = (const float*)d_in[6];
  const float* g2  = (const float*)d_in[7];
  const float* b2  = (const float*)d_in[8];
  const float* m2  = (const float*)d_in[9];
  const float* v2  = (const float*)d_in[10];
  const float* wr1 = (const float*)d_in[11];
  const float* gr1 = (const float*)d_in[12];
  const float* br1 = (const float*)d_in[13];
  const float* mr1 = (const float*)d_in[14];
  const float* vr1 = (const float*)d_in[15];
  const float* wr2 = (const float*)d_in[16];
  const float* gr2 = (const float*)d_in[17];
  const float* br2 = (const float*)d_in[18];
  const float* mr2 = (const float*)d_in[19];
  const float* vr2 = (const float*)d_in[20];
  const float* wr3 = (const float*)d_in[21];
  const float* gr3 = (const float*)d_in[22];
  const float* br3 = (const float*)d_in[23];
  const float* mr3 = (const float*)d_in[24];
  const float* vr3 = (const float*)d_in[25];
  float* out = (float*)d_out;

  char* ws = (char*)d_ws;
  float*          feat  = (float*)ws;                        // 409600 B
  unsigned short* Apack = (unsigned short*)(ws + 819200);    // 294912 B
  float*          Pfx   = (float*)(ws + 1114112);            // 131584 B
  float*          Wt    = (float*)(ws + 1245696);            // 589824 B
  float*          featT = (float*)(ws + 1901056);            // 409600 B
  float*          wr1T  = (float*)(ws + 2310656);            // 131072 B

  prep_kernel<<<380, 256, 0, stream>>>(x, w1, g1, b1, m1, v1, wr2, wr1,
                                       feat, featT, Apack, Pfx, Wt, wr1T);
  rel_kernel<<<800, 512, 0, stream>>>(feat, featT, wr1T, Pfx, gr1, br1, mr1, vr1,
                                      Apack, Wt,
                                      gr2, br2, mr2, vr2, wr3, gr3, br3, mr3, vr3,
                                      x, w2, g2, b2, m2, v2, out);
}